// Round 1
// baseline (248.732 us; speedup 1.0000x reference)
//
#include <hip/hip_runtime.h>
#include <math.h>

#define NUM_CLASSES 10
#define A_BLOCKS 512
#define B_BLOCKS 2048

// ws layout (every used word overwritten each call; no memset, no atomics):
//   [0)     unsigned pc[A_BLOCKS][NUM_CLASSES]  per-block histograms (20480 B)
//   [20480) float2   pacc[B_BLOCKS]             per-block partials   (16384 B)
//
// R5 post-mortem: global_load_lds staging + barrier-coupled phases ran at
// ~1.7 B/cy/CU. Stream loop must stay barrier-free -> this version uses
// wave-PRIVATE LDS staging (intra-wave lgkmcnt ordering only, no
// __syncthreads in the loop) to get coalesced 16B-lane-stride global loads
// instead of the previous 80B-lane-stride pattern (64 vs 16 granules/instr).

__global__ void __launch_bounds__(256) hist_kernel(const int* __restrict__ target,
                                                   unsigned int* __restrict__ pc, int n) {
    unsigned int cnt[NUM_CLASSES];
#pragma unroll
    for (int c = 0; c < NUM_CLASSES; ++c) cnt[c] = 0u;

    const int tid = blockIdx.x * blockDim.x + threadIdx.x;
    const int stride = gridDim.x * blockDim.x;
    const int4* __restrict__ t4 = (const int4*)target;  // harness passes int32 targets
    const int n4 = n >> 2;

    // Packed 6-bit-per-class counter: 10 classes * 6 bits = 60 bits.
    // Flush every 8 int4 (32 elems) -> per-class count <= 32 < 63 cap.
    unsigned long long acc = 0ull;
    int pend = 0;
    for (int i = tid; i < n4; i += stride) {
        int4 v = t4[i];
        acc += (1ull << (6 * v.x)) + (1ull << (6 * v.y)) +
               (1ull << (6 * v.z)) + (1ull << (6 * v.w));
        if (++pend == 8) {
#pragma unroll
            for (int c = 0; c < NUM_CLASSES; ++c)
                cnt[c] += (unsigned int)((acc >> (6 * c)) & 63ull);
            acc = 0ull;
            pend = 0;
        }
    }
#pragma unroll
    for (int c = 0; c < NUM_CLASSES; ++c)
        cnt[c] += (unsigned int)((acc >> (6 * c)) & 63ull);

#pragma unroll
    for (int c = 0; c < NUM_CLASSES; ++c) {
        unsigned int v = cnt[c];
        for (int off = 32; off > 0; off >>= 1)
            v += (unsigned int)__shfl_down((int)v, off, 64);
        cnt[c] = v;
    }

    __shared__ unsigned int sh[4][NUM_CLASSES];
    const int wave = threadIdx.x >> 6;
    if ((threadIdx.x & 63) == 0) {
#pragma unroll
        for (int c = 0; c < NUM_CLASSES; ++c) sh[wave][c] = cnt[c];
    }
    __syncthreads();
    if (threadIdx.x < NUM_CLASSES) {
        const int c = threadIdx.x;
        pc[blockIdx.x * NUM_CLASSES + c] = sh[0][c] + sh[1][c] + sh[2][c] + sh[3][c];
    }
}

__device__ __forceinline__ void compute_pair(const float4 r[5], const float w[NUM_CLASSES],
                                             float& sum_log, float& sumsq) {
    float r0[NUM_CLASSES] = {r[0].x, r[0].y, r[0].z, r[0].w,
                             r[1].x, r[1].y, r[1].z, r[1].w, r[2].x, r[2].y};
    float r1[NUM_CLASSES] = {r[2].z, r[2].w, r[3].x, r[3].y,
                             r[3].z, r[3].w, r[4].x, r[4].y, r[4].z, r[4].w};
    float nom0 = 0.f, nom1 = 0.f;
#pragma unroll
    for (int c = 0; c < NUM_CLASSES; ++c) {
        nom0 += r0[c] * w[c];
        nom1 += r1[c] * w[c];
        sumsq += r0[c] * r0[c] + r1[c] * r1[c];
    }
    sum_log += __logf(nom0) + __logf(nom1);
}

__device__ __forceinline__ void process_pair_direct(const float4* __restrict__ o4, size_t p,
                                                    const float w[NUM_CLASSES],
                                                    float& sum_log, float& sumsq) {
    const float4* base = o4 + p * 5;
    float4 r[5] = {base[0], base[1], base[2], base[3], base[4]};
    compute_pair(r, w, sum_log, sumsq);
}

__global__ void __launch_bounds__(256) main_kernel(const float* __restrict__ outputs,
                                                   const unsigned int* __restrict__ pc,
                                                   float2* __restrict__ pacc, int n) {
    const int wave = threadIdx.x >> 6;
    const int lane = threadIdx.x & 63;

    // ---- phase 1: reduce per-block histograms -> w[10] (block-local) ----
    unsigned int pw[NUM_CLASSES];
#pragma unroll
    for (int c = 0; c < NUM_CLASSES; ++c) pw[c] = 0u;
#pragma unroll
    for (int r = 0; r < A_BLOCKS / 256; ++r) {
        const unsigned int* row = pc + (threadIdx.x + r * 256) * NUM_CLASSES;
#pragma unroll
        for (int c = 0; c < NUM_CLASSES; ++c) pw[c] += row[c];
    }
#pragma unroll
    for (int c = 0; c < NUM_CLASSES; ++c) {
        unsigned int v = pw[c];
        for (int off = 32; off > 0; off >>= 1)
            v += (unsigned int)__shfl_down((int)v, off, 64);
        pw[c] = v;
    }
    __shared__ unsigned int shw[4][NUM_CLASSES];
    __shared__ float fw[NUM_CLASSES];
    if (lane == 0) {
#pragma unroll
        for (int c = 0; c < NUM_CLASSES; ++c) shw[wave][c] = pw[c];
    }
    __syncthreads();
    if (threadIdx.x < NUM_CLASSES) {
        const int c = threadIdx.x;
        fw[c] = (float)(shw[0][c] + shw[1][c] + shw[2][c] + shw[3][c]);
    }
    __syncthreads();
    float w[NUM_CLASSES];
#pragma unroll
    for (int c = 0; c < NUM_CLASSES; ++c) w[c] = fw[c];

    // ---- phase 2: coalesced stream via wave-private LDS transpose ----
    // Tile = 64 pairs (128 rows) = 320 float4 = 5120 B per wave, 1024-B aligned.
    // Load k=0..4: lane reads src[k*64 + lane]  -> 1024 B contiguous per instr.
    // Stage to wave-private LDS at slot = c*64 + (p ^ c)  (c = f4 % 5, p = f4 / 5):
    //   reads (fixed c, lanes l -> slot c*64 + (l^c)) are a permutation of a
    //   contiguous 1 KiB block -> conflict-free; writes spread uniformly.
    // No __syncthreads in this loop: region is wave-private, lgkmcnt orders it.
    __shared__ float4 stage[4][5 * 64];  // 20 KiB
    float4* my = stage[wave];

    int wslot[5], rslot[5];
#pragma unroll
    for (int k = 0; k < 5; ++k) {
        const int j = k * 64 + lane;
        const int c = j % 5;
        const int p = j / 5;
        wslot[k] = c * 64 + (p ^ c);
        rslot[k] = k * 64 + (lane ^ k);
    }

    const float4* __restrict__ o4 = (const float4*)outputs;
    const int npairs = n >> 1;           // 2^21
    const int ntiles = npairs >> 6;      // 32768
    const int gw = blockIdx.x * 4 + wave;       // global wave id, 0..8191
    const int nwaves = gridDim.x * 4;           // 8192 -> exactly 4 tiles/wave

    float sum_log = 0.f, sumsq = 0.f;
    for (int tile = gw; tile < ntiles; tile += nwaves) {
        const float4* src = o4 + (size_t)tile * 320;
        float4 g[5];
#pragma unroll
        for (int k = 0; k < 5; ++k) g[k] = src[k * 64 + lane];
#pragma unroll
        for (int k = 0; k < 5; ++k) my[wslot[k]] = g[k];
        float4 r[5];
#pragma unroll
        for (int k = 0; k < 5; ++k) r[k] = my[rslot[k]];
        compute_pair(r, w, sum_log, sumsq);
    }

    // tail (empty for n = 2^22, kept for generality)
    const int done = ntiles << 6;
    const int tid = blockIdx.x * blockDim.x + threadIdx.x;
    for (int p = done + tid; p < npairs; p += gridDim.x * blockDim.x)
        process_pair_direct(o4, (size_t)p, w, sum_log, sumsq);

    // ---- phase 3: block reduce, plain store of per-block partial ----
    for (int off = 32; off > 0; off >>= 1) {
        sum_log += __shfl_down(sum_log, off, 64);
        sumsq += __shfl_down(sumsq, off, 64);
    }
    __shared__ float s1[4], s2[4];
    if (lane == 0) { s1[wave] = sum_log; s2[wave] = sumsq; }
    __syncthreads();
    if (threadIdx.x == 0) {
        pacc[blockIdx.x] = make_float2(s1[0] + s1[1] + s1[2] + s1[3],
                                       s2[0] + s2[1] + s2[2] + s2[3]);
    }
}

__global__ void __launch_bounds__(256) finalize_kernel(const float2* __restrict__ pacc,
                                                       float* __restrict__ out, float fn) {
    float sum_log = 0.f, sumsq = 0.f;
    for (int i = threadIdx.x; i < B_BLOCKS; i += 256) {
        float2 v = pacc[i];
        sum_log += v.x;
        sumsq += v.y;
    }
    for (int off = 32; off > 0; off >>= 1) {
        sum_log += __shfl_down(sum_log, off, 64);
        sumsq += __shfl_down(sumsq, off, 64);
    }
    __shared__ float s1[4], s2[4];
    const int wave = threadIdx.x >> 6;
    if ((threadIdx.x & 63) == 0) { s1[wave] = sum_log; s2[wave] = sumsq; }
    __syncthreads();
    if (threadIdx.x == 0) {
        float t1 = s1[0] + s1[1] + s1[2] + s1[3];
        float t2 = s2[0] + s2[1] + s2[2] + s2[3];
        // mean(-log(nom/denom)) = 0.5*log(sumsq) + 0.5*log(N) - sum_log/N
        out[0] = 0.5f * logf(t2) + 0.5f * logf(fn) - t1 / fn;
    }
}

extern "C" void kernel_launch(void* const* d_in, const int* in_sizes, int n_in,
                              void* d_out, int out_size, void* d_ws, size_t ws_size,
                              hipStream_t stream) {
    const float* outputs = (const float*)d_in[0];
    const int* target = (const int*)d_in[1];
    const int n = in_sizes[1];

    unsigned int* pc = (unsigned int*)d_ws;
    float2* pacc = (float2*)((char*)d_ws + 20480);

    hist_kernel<<<A_BLOCKS, 256, 0, stream>>>(target, pc, n);
    main_kernel<<<B_BLOCKS, 256, 0, stream>>>(outputs, pc, pacc, n);
    finalize_kernel<<<1, 256, 0, stream>>>(pacc, (float*)d_out, (float)n);
}